// Round 9
// baseline (349.324 us; speedup 1.0000x reference)
//
#include <hip/hip_runtime.h>

// ---------------------------------------------------------------------------
// AttnBlock: GroupNorm -> QKV (1x1 conv) -> 4-head attention (L=2048, hd=128)
//            -> out proj -> residual.   B=8, C=512, L=2048, G=4, NH=4.
// Storage dtype: float32. Internal compute: bf16 MFMA, f32 accumulation.
// R9: producer-consumer wave specialization in attention. 256-thread blocks:
//     waves 0-1 = S-waves (QK^T + softmax + P, M=32 -> kf reused 2x),
//     waves 2-3 = PV-waves (P(t-1)*V(t-1) -> O, vf reused 2x). S(t) and
//     PV(t-1) overlap across waves -> serial chain halved. j-tile 32,
//     2 barriers/iter, K full-iter DMA flight (vm<=4), V staged 1 tile
//     ahead of consumer. 41KB LDS -> 3 blocks/CU (12 waves). XCD-aware
//     block swizzle: each XCD owns 4 (b,h) -> K/V L2-resident.
// ---------------------------------------------------------------------------

typedef unsigned short u16;
typedef unsigned int   u32;
typedef unsigned long long u64;
typedef __attribute__((ext_vector_type(8)))  short          bf16x8;  // MFMA A/B frag
typedef __attribute__((ext_vector_type(4)))  float          f32x4;   // MFMA C/D frag
typedef __attribute__((ext_vector_type(4)))  unsigned int   u32x4;   // 16B copy
typedef __attribute__((ext_vector_type(8)))  unsigned short u16x8;

#define MFMA16(a, b, c) __builtin_amdgcn_mfma_f32_16x16x32_bf16((a), (b), (c), 0, 0, 0)

// s_waitcnt simm16: vmcnt[3:0]=bits3:0 (+bits15:14), expcnt=bits6:4, lgkmcnt=bits11:8
#define WAIT_VM4       3956   // vm<=4, exp/lgkm untouched (0xF74)
#define WAIT_VM2       3954   // vm<=2 (0xF72)
#define WAIT_LGKM0    49279   // lgkm=0, vm untouched (0xC07F)
#define WAIT_VM0_LGKM0  112   // vm=0, lgkm=0 (0x70)
#define BARRIER() __builtin_amdgcn_s_barrier()

__device__ __forceinline__ u16 f2bf(float f) {
    union { float f; unsigned int i; } cv;
    cv.f = f;
    unsigned int u = cv.i;
    u += 0x7fffu + ((u >> 16) & 1);   // RNE
    return (u16)(u >> 16);
}
__device__ __forceinline__ u32 fbits(float f) {
    union { float f; unsigned int i; } cv; cv.f = f; return cv.i;
}

// async 16B global->LDS (DMA; lands at lds_base + lane*16)
__device__ __forceinline__ void async16(const u16* g, u16* l) {
    __builtin_amdgcn_global_load_lds(
        (const __attribute__((address_space(1))) unsigned int*)g,
        (__attribute__((address_space(3))) unsigned int*)l, 16, 0, 0);
}

#define BATCH 8
#define CCH   512
#define LEN   2048
#define NGRP  4
#define NHEAD 4
#define HD    128
#define GSIZE (128 * 2048)   // elements per (b, group)

// ---------------------------------------------------------------------------
// 0) Convert the four 512x512 f32 weight matrices to bf16 (once per launch).
// ---------------------------------------------------------------------------
__global__ __launch_bounds__(256) void wcvt_k(const float* __restrict__ w0,
                                              const float* __restrict__ w1,
                                              const float* __restrict__ w2,
                                              const float* __restrict__ w3,
                                              u16* __restrict__ dst) {
    const int mat = blockIdx.y;
    const float* src = (mat == 0) ? w0 : (mat == 1) ? w1 : (mat == 2) ? w2 : w3;
    const size_t base = (size_t)blockIdx.x * 2048 + (size_t)threadIdx.x * 8;
    f32x4 a = *(const f32x4*)(src + base);
    f32x4 b = *(const f32x4*)(src + base + 4);
    u16x8 o;
    for (int u = 0; u < 4; ++u) { o[u] = f2bf(a[u]); o[u + 4] = f2bf(b[u]); }
    *(u16x8*)(dst + (size_t)mat * 262144 + base) = o;
}

// ---------------------------------------------------------------------------
// 1) GroupNorm partial stats (f32 input): 256 blocks, 16 channels of one (b,g).
// ---------------------------------------------------------------------------
__global__ __launch_bounds__(256) void gn_stats_k(const float* __restrict__ x,
                                                  float* __restrict__ stats) {
    const int bid   = blockIdx.x;       // 0..255
    const int grp   = bid >> 3;         // b*4+g
    const int chunk = bid & 7;          // 16-channel slab
    const int b = grp >> 2, g = grp & 3;
    const float* base = x + ((size_t)(b * CCH + g * 128 + chunk * 16)) * LEN;

    float s = 0.f, ss = 0.f;
    for (int i = 0; i < 32; ++i) {
        int cid = threadIdx.x + i * 256;          // 0..8191 chunks of 4
        f32x4 dv = *(const f32x4*)(base + (size_t)cid * 4);
        for (int u = 0; u < 4; ++u) { s += dv[u]; ss += dv[u] * dv[u]; }
    }
    for (int m = 1; m < 64; m <<= 1) {
        s  += __shfl_xor(s,  m, 64);
        ss += __shfl_xor(ss, m, 64);
    }
    __shared__ float red[8];
    int wid = threadIdx.x >> 6, lane = threadIdx.x & 63;
    if (lane == 0) { red[wid * 2] = s; red[wid * 2 + 1] = ss; }
    __syncthreads();
    if (threadIdx.x == 0) {
        float ts  = red[0] + red[2] + red[4] + red[6];
        float tss = red[1] + red[3] + red[5] + red[7];
        atomicAdd(&stats[grp * 2],     ts);
        atomicAdd(&stats[grp * 2 + 1], tss);
    }
}

// ---------------------------------------------------------------------------
// 2) GroupNorm apply + transpose: x[b,c,l] (f32) -> hT[b,l,c] (bf16).
//    64x64 tiles through LDS.
// ---------------------------------------------------------------------------
__global__ __launch_bounds__(256) void gn_apply_k(const float* __restrict__ x,
                                                  const float* __restrict__ gns,
                                                  const float* __restrict__ gnb,
                                                  const float* __restrict__ stats,
                                                  u16* __restrict__ hT) {
    __shared__ u16 Ts[64 * 72];
    const int b = blockIdx.z, c0 = blockIdx.y * 64, l0 = blockIdx.x * 64;
    const int g = c0 >> 7;
    const int tid = threadIdx.x;

    float sum   = stats[(b * NGRP + g) * 2];
    float sumsq = stats[(b * NGRP + g) * 2 + 1];
    const float invN = 1.f / (float)GSIZE;
    float mean = sum * invN;
    float var  = sumsq * invN - mean * mean;
    float rstd = rsqrtf(var + 1e-6f);

    for (int i = 0; i < 4; ++i) {
        int cid = tid + i * 256;          // 0..1023
        int row = cid >> 4, c4 = cid & 15; // row = channel in tile, col = c4*4
        int c = c0 + row;
        float sc = gns[c] * rstd;
        float bi = gnb[c] - mean * sc;
        f32x4 dv = *(const f32x4*)(x + ((size_t)(b * CCH + c)) * LEN + l0 + c4 * 4);
        for (int u = 0; u < 4; ++u)
            Ts[row * 72 + c4 * 4 + u] = f2bf(dv[u] * sc + bi);
    }
    __syncthreads();
    for (int i = 0; i < 2; ++i) {
        int cid = tid + i * 256;          // 0..511
        int lrow = cid >> 3, c8 = cid & 7;
        u16x8 ov;
        for (int u = 0; u < 8; ++u) ov[u] = Ts[(c8 * 8 + u) * 72 + lrow];
        *(u16x8*)(hT + ((size_t)b * LEN + l0 + lrow) * CCH + c0 + c8 * 8) = ov;
    }
}

// ---------------------------------------------------------------------------
// GEMM: D[m][n] = sum_k A[m][k]*B[n][k]; operands row-major [row, 512] bf16.
// MODE 0: A=hT[b] (m=l), B=wq_bf/wk_bf (n=o, N=1024) -> qT/kT (bf16) + bias
// MODE 1: A=wv_bf (m=o), B=hT[b] (n=l) -> v[b,c,l] (bf16) + bias
// MODE 2: A=wo_bf (m=o), B=attnT[b] (n=l) -> out[b,c,l] (f32) + bias + x
// 128x128x(K=512) tiles, BK=64, 4 waves (2x2), 64 f32 acc/lane.
// Staging: double-buffered global_load_lds (issue k+1 before compute k).
// ---------------------------------------------------------------------------
template <int MODE>
__global__ __launch_bounds__(256, 2) void gemm_k(const u16* __restrict__ A0,
                                                 const u16* __restrict__ B0,
                                                 const u16* __restrict__ B1,
                                                 const float* __restrict__ bias0,
                                                 const float* __restrict__ bias1,
                                                 const float* __restrict__ resid,
                                                 void* __restrict__ out0v,
                                                 u16* __restrict__ out1) {
    __shared__ u16 As[2][128 * 64];
    __shared__ u16 Bs[2][128 * 64];
    const int b  = blockIdx.z;
    const int n0 = blockIdx.x * 128;
    const int m0 = blockIdx.y * 128;
    const int tid = threadIdx.x;
    const int lane = tid & 63, wid = tid >> 6;
    const int quad = lane >> 4, l15 = lane & 15;
    const int wm = (wid & 1) * 64, wn = (wid >> 1) * 64;

    const u16* Arow;
    if constexpr (MODE == 0) Arow = A0 + ((size_t)b * LEN + m0) * 512;
    else                     Arow = A0 + (size_t)m0 * 512;

    const u16* Brow;
    int col0 = 0;
    if constexpr (MODE == 0) {
        if (n0 < 512) { Brow = B0 + (size_t)n0 * 512;         col0 = n0; }
        else          { Brow = B1 + (size_t)(n0 - 512) * 512;  col0 = n0 - 512; }
    } else {
        Brow = B0 + ((size_t)b * LEN + n0) * 512;
    }

    f32x4 acc[4][4] = {};
    const int srl = lane >> 3, scl = lane & 7;   // 8 rows/instr, chunk lane&7

    // prologue: stage k-tile 0 into buffer 0
#pragma unroll
    for (int i = 0; i < 4; ++i) {
        int rloc = wid * 32 + i * 8 + srl;
        int lc = scl ^ (rloc & 7);
        async16(Arow + (size_t)rloc * 512 + lc * 8, &As[0][(wid * 32 + i * 8) * 64]);
        async16(Brow + (size_t)rloc * 512 + lc * 8, &Bs[0][(wid * 32 + i * 8) * 64]);
    }
    __syncthreads();

    for (int kk = 0; kk < 8; ++kk) {
        const int p = kk & 1;
        if (kk < 7) {            // issue next tile's DMA; drained by end barrier
            const int k0n = (kk + 1) * 64;
#pragma unroll
            for (int i = 0; i < 4; ++i) {
                int rloc = wid * 32 + i * 8 + srl;
                int lc = scl ^ (rloc & 7);
                async16(Arow + (size_t)rloc * 512 + k0n + lc * 8,
                        &As[1 - p][(wid * 32 + i * 8) * 64]);
                async16(Brow + (size_t)rloc * 512 + k0n + lc * 8,
                        &Bs[1 - p][(wid * 32 + i * 8) * 64]);
            }
        }
#pragma unroll
        for (int ks = 0; ks < 2; ++ks) {
            bf16x8 af[4], bfr[4];
            for (int t = 0; t < 4; ++t) {
                int ra = wm + t * 16 + l15, rb = wn + t * 16 + l15;
                af[t]  = *(const bf16x8*)(&As[p][ra * 64 + (((ks * 4 + quad) ^ (ra & 7))) * 8]);
                bfr[t] = *(const bf16x8*)(&Bs[p][rb * 64 + (((ks * 4 + quad) ^ (rb & 7))) * 8]);
            }
            for (int mt = 0; mt < 4; ++mt)
                for (int nt = 0; nt < 4; ++nt)
                    acc[mt][nt] = MFMA16(af[mt], bfr[nt], acc[mt][nt]);
        }
        __syncthreads();   // reads of [p] done; DMA(kk+1) drained (flew over MFMA)
    }

    if constexpr (MODE == 0) {
        const float* biasp = (n0 < 512) ? (bias0 + col0) : (bias1 + col0);
        u16* outp = (n0 < 512) ? (u16*)out0v : out1;
        for (int nt = 0; nt < 4; ++nt) {
            int nl = wn + nt * 16 + l15;
            float bv_ = biasp[nl];
            for (int mt = 0; mt < 4; ++mt)
                for (int r = 0; r < 4; ++r) {
                    int ml = wm + mt * 16 + quad * 4 + r;
                    size_t idx = ((size_t)b * LEN + m0 + ml) * 512 + col0 + nl;
                    outp[idx] = f2bf(acc[mt][nt][r] + bv_);
                }
        }
    } else {
        for (int mt = 0; mt < 4; ++mt)
            for (int r = 0; r < 4; ++r) {
                int ml = wm + mt * 16 + quad * 4 + r;
                float bv_ = bias0[m0 + ml];
                for (int nt = 0; nt < 4; ++nt) {
                    int nl = wn + nt * 16 + l15;
                    size_t idx = ((size_t)(b * 512 + m0 + ml)) * LEN + n0 + nl;
                    float val = acc[mt][nt][r] + bv_;
                    if constexpr (MODE == 2) {
                        ((float*)out0v)[idx] = val + resid[idx];
                    } else {
                        ((u16*)out0v)[idx] = f2bf(val);
                    }
                }
            }
    }
}

// ---------------------------------------------------------------------------
// Flash attention v8: producer-consumer wave specialization.
// 256-thread blocks, Q-tile 64 rows, j-tiles of 32 keys, 64 iterations.
// Waves 0-1 (S): QK^T (A=K from LDS, B=Q regs; M=32, kf reused 2x),
//   per-lane online softmax, P(t)+alpha(t) -> LDS.
// Waves 2-3 (PV): rescale O by alpha(t-1), O += P(t-1)*V(t-1) (vf 2x reuse).
// Pipeline per iter t: issue V(t)->Vs[p], K(t+1)->Ks[1-p]; vm<=4 (K(t),V(t-1)
// landed, full-iter flight); barrier; S(t) || PV(t-1); lgkm0; barrier.
// LDS 41KB -> 3 blocks/CU = 12 waves/CU. Grid 1024 XCD-swizzled (each XCD
// owns 4 (b,h) pairs -> K/V resident in its 4MB L2).
// ---------------------------------------------------------------------------
__global__ __launch_bounds__(256, 3) void attn_k(const u16* __restrict__ qT,
                                                 const u16* __restrict__ kT,
                                                 const u16* __restrict__ v,
                                                 u16* __restrict__ attnT) {
    __shared__ u16  Ks[2][32 * 128];   // K tiles (dbuf)
    __shared__ u16  Vs[2][128 * 32];   // V tiles (dbuf)
    __shared__ u16  Ps[2][2][32 * 32]; // P tiles (dbuf x m-group)
    __shared__ float Al[2][2][32];     // alpha (dbuf x m-group x m-local)
    __shared__ float Lf[2][32];        // final l per m-group
    const int bid = blockIdx.x;
    const int xcd = bid & 7, slot = bid >> 3;
    const int bh  = xcd * 4 + (slot >> 5);     // each XCD: 4 (b,h) pairs
    const int qt  = slot & 31;
    const int b = bh >> 2, h = bh & 3;
    const int i0 = qt * 64;

    const int tid = threadIdx.x, lane = tid & 63, wid = tid >> 6;
    const int quad = lane >> 4, l15 = lane & 15;
    const bool isS = (wid < 2);
    const int mg = wid & 1;            // m-group (32 rows) for both roles

    const float SL2E = 0.08838834764831845f * 1.4426950408889634f; // scale*log2e

    // staging: 2 K-loads + 2 V-loads per thread per iter, loop-carried ptrs
    const u16* kbase = kT + ((size_t)b * LEN) * 512 + h * HD;
    const u16* vbase = v + ((size_t)(b * CCH + h * HD)) * LEN;
    const u16* kp[2];
    const u16* vp[2];
    int krow[2], vrow[2];
#pragma unroll
    for (int i = 0; i < 2; ++i) {
        int rk = (wid * 2 + i) * 4 + (lane >> 4);      // K row in tile 0..31
        krow[i] = (wid * 2 + i) * 4;
        kp[i] = kbase + (size_t)rk * 512 + ((lane & 15) ^ (rk & 7)) * 8;
        int rd = (wid * 2 + i) * 16 + (lane >> 2);     // V row (d) 0..127
        vrow[i] = (wid * 2 + i) * 16;
        vp[i] = vbase + (size_t)rd * LEN + ((lane & 3) ^ (rd & 3)) * 8;
    }

    // S-wave Q fragments (B-operand), 32 m-rows
    bf16x8 qa[2][4];
    if (isS) {
        for (int mf = 0; mf < 2; ++mf)
            for (int ks = 0; ks < 4; ++ks) {
                int m = i0 + mg * 32 + mf * 16 + l15;
                qa[mf][ks] = *(const bf16x8*)(qT + ((size_t)b * LEN + m) * 512 + h * HD +
                                              ks * 32 + quad * 8);
            }
    }
    float mst[2] = {-3.0e38f, -3.0e38f}, lst[2] = {0.f, 0.f};   // S state
    f32x4 oacc[2][8] = {};                                      // PV state

    // prologue: stage K(0) into Ks[0]
#pragma unroll
    for (int i = 0; i < 2; ++i) { async16(kp[i], &Ks[0][krow[i] * 128]); kp[i] += 32 * 512; }

    for (int t = 0; t < 64; ++t) {
        const int p = t & 1;
        // issue V(t) -> Vs[p] (consumed by PV at t+1: full-iter flight)
#pragma unroll
        for (int i = 0; i < 2; ++i) { async16(vp[i], &Vs[p][vrow[i] * 32]); vp[i] += 32; }
        // issue K(t+1) -> Ks[1-p]
        if (t < 63) {
#pragma unroll
            for (int i = 0; i < 2; ++i) {
                async16(kp[i], &Ks[1 - p][krow[i] * 128]);
                if (t < 62) kp[i] += 32 * 512;
            }
            __builtin_amdgcn_s_waitcnt(WAIT_VM4);   // K(t), V(t-1) landed (mine)
        } else {
            __builtin_amdgcn_s_waitcnt(WAIT_VM2);   // no K issued this iter
        }
        BARRIER();   // K(t), V(t-1) visible to all waves

        if (isS) {
            // ---- S role: QK^T (S^T tile: rows j 0..31, cols m 0..31) ----
            f32x4 st[2][2] = {};
#pragma unroll
            for (int jtn = 0; jtn < 2; ++jtn) {
                int r = jtn * 16 + l15;
                for (int ks = 0; ks < 4; ++ks) {
                    bf16x8 kf = *(const bf16x8*)(&Ks[p][r * 128 + ((ks * 4 + quad) ^ (r & 7)) * 8]);
                    st[0][jtn] = MFMA16(kf, qa[0][ks], st[0][jtn]);
                    st[1][jtn] = MFMA16(kf, qa[1][ks], st[1][jtn]);
                }
            }
#pragma unroll
            for (int mf = 0; mf < 2; ++mf) {
                float rm = -3.0e38f;
                for (int jtn = 0; jtn < 2; ++jtn)
                    for (int r = 0; r < 4; ++r) rm = fmaxf(rm, st[mf][jtn][r]);
                rm *= SL2E;
                rm = fmaxf(rm, __shfl_xor(rm, 16, 64));
                rm = fmaxf(rm, __shfl_xor(rm, 32, 64));
                float mnew  = fmaxf(mst[mf], rm);
                float alpha = __builtin_amdgcn_exp2f(mst[mf] - mnew);
                mst[mf] = mnew;
                float rs = 0.f;
                for (int jtn = 0; jtn < 2; ++jtn)
                    for (int r = 0; r < 4; ++r) {
                        float pv_ = __builtin_amdgcn_exp2f(st[mf][jtn][r] * SL2E - mnew);
                        st[mf][jtn][r] = pv_;
                        rs += pv_;
                    }
                rs += __shfl_xor(rs, 16, 64);
                rs += __shfl_xor(rs, 32, 64);
                lst[mf] = lst[mf] * alpha + rs;
                if (quad == 0) Al[p][mg][mf * 16 + l15] = alpha;
                // P[m][j] bf16 (half-up) -> Ps[p][mg], swizzled b64
                int ml = mf * 16 + l15;
                for (int jtn = 0; jtn < 2; ++jtn) {
                    u64 packed =  (u64)((fbits(st[mf][jtn][0]) + 0x8000u) >> 16)
                               | ((u64)((fbits(st[mf][jtn][1]) + 0x8000u) >> 16) << 16)
                               | ((u64)((fbits(st[mf][jtn][2]) + 0x8000u) >> 16) << 32)
                               | ((u64)((fbits(st[mf][jtn][3]) + 0x8000u) >> 16) << 48);
                    int pc = (jtn * 2 + (quad >> 1)) ^ (ml & 3);
                    *(u64*)(&Ps[p][mg][ml * 32 + pc * 8 + (quad & 1) * 4]) = packed;
                }
            }
        } else if (t > 0) {
            // ---- PV role: O = O*alpha(t-1) + P(t-1) * V(t-1) ----
            f32x4 av[2];
            for (int mf = 0; mf < 2; ++mf)
                av[mf] = *(const f32x4*)(&Al[1 - p][mg][mf * 16 + quad * 4]);
            bool resc = (av[0][0] != 1.f) || (av[0][1] != 1.f) || (av[0][2] != 1.f) ||
                        (av[0][3] != 1.f) || (av[1][0] != 1.f) || (av[1][1] != 1.f) ||
                        (av[1][2] != 1.f) || (av[1][3] != 1.f);
            if (__ballot(resc) != 0ull) {
                for (int mf = 0; mf < 2; ++mf)
                    for (int dt = 0; dt < 8; ++dt)
                        for (int r = 0; r < 4; ++r) oacc[mf][dt][r] *= av[mf][r];
            }
            bf16x8 pf[2];
            for (int mf = 0; mf < 2; ++mf) {
                int ml = mf * 16 + l15;
                pf[mf] = *(const bf16x8*)(&Ps[1 - p][mg][ml * 32 + (quad ^ (ml & 3)) * 8]);
            }
            for (int dt = 0; dt < 8; ++dt) {
                int d = dt * 16 + l15;
                bf16x8 vf = *(const bf16x8*)(&Vs[1 - p][d * 32 + (quad ^ (d & 3)) * 8]);
                oacc[0][dt] = MFMA16(pf[0], vf, oacc[0][dt]);
                oacc[1][dt] = MFMA16(pf[1], vf, oacc[1][dt]);
            }
        }

        __builtin_amdgcn_s_waitcnt(WAIT_LGKM0);  // my LDS ops retired
        BARRIER();                               // P(t)/Al(t) visible; slots reusable
    }

    // epilogue: S publishes final l; PV consumes tile 63 and writes out
    if (isS && quad == 0) {
        Lf[mg][l15]      = lst[0];
        Lf[mg][16 + l15] = lst[1];
    }
    __builtin_amdgcn_s_waitcnt(WAIT_VM0_LGKM0);  // V(63) landed; Lf written
    BARRIER();

    if (!isS) {
        // PV(63): p=1 buffers
        f32x4 av[2];
        for (int mf = 0; mf < 2; ++mf)
            av[mf] = *(const f32x4*)(&Al[1][mg][mf * 16 + quad * 4]);
        for (int mf = 0; mf < 2; ++mf)
            for (int dt = 0; dt < 8; ++dt)
                for (int r = 0; r < 4; ++r) oacc[mf][dt][r] *= av[mf][r];
        bf16x8 pf[2];
        for (int mf = 0; mf < 2; ++mf) {
            int ml = mf * 16 + l15;
            pf[mf] = *(const bf16x8*)(&Ps[1][mg][ml * 32 + (quad ^ (ml & 3)) * 8]);
        }
        for (int dt = 0; dt < 8; ++dt) {
            int d = dt * 16 + l15;
            bf16x8 vf = *(const bf16x8*)(&Vs[1][d * 32 + (quad ^ (d & 3)) * 8]);
            oacc[0][dt] = MFMA16(pf[0], vf, oacc[0][dt]);
            oacc[1][dt] = MFMA16(pf[1], vf, oacc[1][dt]);
        }
        // normalize by final l and store attnT[b, m, c]
        for (int mf = 0; mf < 2; ++mf) {
            f32x4 lf = *(const f32x4*)(&Lf[mg][mf * 16 + quad * 4]);
            for (int r = 0; r < 4; ++r) {
                float inv = 1.f / lf[r];
                int m = i0 + mg * 32 + mf * 16 + quad * 4 + r;
                for (int dt = 0; dt < 8; ++dt) {
                    int d = dt * 16 + l15;
                    attnT[((size_t)b * LEN + m) * 512 + h * HD + d] =
                        f2bf(oacc[mf][dt][r] * inv);
                }
            }
        }
    }
}

// ---------------------------------------------------------------------------
extern "C" void kernel_launch(void* const* d_in, const int* in_sizes, int n_in,
                              void* d_out, int out_size, void* d_ws, size_t ws_size,
                              hipStream_t stream) {
    const float* x   = (const float*)d_in[0];
    const float* gns = (const float*)d_in[1];
    const float* gnb = (const float*)d_in[2];
    const float* wq  = (const float*)d_in[3];
    const float* bq  = (const float*)d_in[4];
    const float* wk  = (const float*)d_in[5];
    const float* bk  = (const float*)d_in[6];
    const float* wv  = (const float*)d_in[7];
    const float* bv  = (const float*)d_in[8];
    const float* wo  = (const float*)d_in[9];
    const float* bo  = (const float*)d_in[10];
    float* out = (float*)d_out;

    const size_t NEL = (size_t)BATCH * CCH * LEN;   // 8388608
    float* stats = (float*)d_ws;                     // 64 floats @ 0
    u16* wcat  = (u16*)((char*)d_ws + 256);          // 4 x 512x512 bf16 weights
    u16* hT    = wcat + 4 * 262144;                  // bf16 [B,L,C]; reused as attnT
    u16* qT    = hT + NEL;
    u16* kT    = qT + NEL;
    u16* vbuf  = kT + NEL;
    u16* attnT = hT;   // hT dead after gemm<1>; alias to save 16 MB

    const u16* wq_bf = wcat;
    const u16* wk_bf = wcat + 262144;
    const u16* wv_bf = wcat + 2 * 262144;
    const u16* wo_bf = wcat + 3 * 262144;

    hipMemsetAsync(d_ws, 0, 256, stream);
    wcvt_k<<<dim3(128, 4), 256, 0, stream>>>(wq, wk, wv, wo, wcat);
    gn_stats_k<<<256, 256, 0, stream>>>(x, stats);
    gn_apply_k<<<dim3(32, 8, 8), 256, 0, stream>>>(x, gns, gnb, stats, hT);
    gemm_k<0><<<dim3(8, 16, 8), 256, 0, stream>>>(hT, wq_bf, wk_bf, bq, bk, nullptr, qT, kT);
    gemm_k<1><<<dim3(16, 4, 8), 256, 0, stream>>>(wv_bf, hT, nullptr, bv, nullptr, nullptr, vbuf, nullptr);
    attn_k<<<dim3(1024), 256, 0, stream>>>(qT, kT, vbuf, attnT);
    gemm_k<2><<<dim3(16, 4, 8), 256, 0, stream>>>(wo_bf, attnT, nullptr, bo, nullptr, x, out, nullptr);
}

// Round 10
// 268.781 us; speedup vs baseline: 1.2997x; 1.2997x over previous
//
#include <hip/hip_runtime.h>

// ---------------------------------------------------------------------------
// AttnBlock: GroupNorm -> QKV (1x1 conv) -> 4-head attention (L=2048, hd=128)
//            -> out proj -> residual.   B=8, C=512, L=2048, G=4, NH=4.
// Storage dtype: float32. Internal compute: bf16 MFMA, f32 accumulation.
// R10: consolidation. attn = R8 structure (512 thr, 8 waves, 64-key j-tiles,
//      partial-vmcnt dbuf) + R9's XCD swizzle (each XCD owns one batch's 4
//      heads -> K/V = 4MB = its L2; R9 proved FETCH 139->29MB). Dispatch
//      count cut 8->6: wcvt+gn_stats fused, gemm<0>+gemm<1> fused (uniform
//      per-block branch). GEMM internals untouched (historically neutral).
// ---------------------------------------------------------------------------

typedef unsigned short u16;
typedef unsigned int   u32;
typedef unsigned long long u64;
typedef __attribute__((ext_vector_type(8)))  short          bf16x8;  // MFMA A/B frag
typedef __attribute__((ext_vector_type(4)))  float          f32x4;   // MFMA C/D frag
typedef __attribute__((ext_vector_type(4)))  unsigned int   u32x4;   // 16B copy
typedef __attribute__((ext_vector_type(8)))  unsigned short u16x8;

#define MFMA16(a, b, c) __builtin_amdgcn_mfma_f32_16x16x32_bf16((a), (b), (c), 0, 0, 0)

// s_waitcnt simm16: vmcnt[3:0] in [3:0] (+[15:14] high), expcnt[6:4], lgkmcnt[11:8]
#define WAIT_VM6         3958   // vm<=6, exp/lgkm untouched
#define WAIT_VM4_LGKM0    116   // vm<=4, lgkm=0
#define BARRIER() __builtin_amdgcn_s_barrier()

__device__ __forceinline__ u16 f2bf(float f) {
    union { float f; unsigned int i; } cv;
    cv.f = f;
    unsigned int u = cv.i;
    u += 0x7fffu + ((u >> 16) & 1);   // RNE
    return (u16)(u >> 16);
}
__device__ __forceinline__ u32 fbits(float f) {
    union { float f; unsigned int i; } cv; cv.f = f; return cv.i;
}

// async 16B global->LDS (DMA; lands at lds_base + lane*16)
__device__ __forceinline__ void async16(const u16* g, u16* l) {
    __builtin_amdgcn_global_load_lds(
        (const __attribute__((address_space(1))) unsigned int*)g,
        (__attribute__((address_space(3))) unsigned int*)l, 16, 0, 0);
}

#define BATCH 8
#define CCH   512
#define LEN   2048
#define NGRP  4
#define NHEAD 4
#define HD    128
#define GSIZE (128 * 2048)   // elements per (b, group)

// ---------------------------------------------------------------------------
// 0) Fused prep: blocks 0..255 = GroupNorm partial stats; 256..767 = weight
//    conversion (4 x 512x512 f32 -> bf16). Independent work, one dispatch.
// ---------------------------------------------------------------------------
__global__ __launch_bounds__(256) void prep_k(const float* __restrict__ x,
                                              float* __restrict__ stats,
                                              const float* __restrict__ w0,
                                              const float* __restrict__ w1,
                                              const float* __restrict__ w2,
                                              const float* __restrict__ w3,
                                              u16* __restrict__ dst) {
    const int bid = blockIdx.x;
    if (bid < 256) {
        // ---- GroupNorm stats: 16-channel slab of one (b,g) ----
        const int grp   = bid >> 3;         // b*4+g
        const int chunk = bid & 7;
        const int b = grp >> 2, g = grp & 3;
        const float* base = x + ((size_t)(b * CCH + g * 128 + chunk * 16)) * LEN;

        float s = 0.f, ss = 0.f;
        for (int i = 0; i < 32; ++i) {
            int cid = threadIdx.x + i * 256;
            f32x4 dv = *(const f32x4*)(base + (size_t)cid * 4);
            for (int u = 0; u < 4; ++u) { s += dv[u]; ss += dv[u] * dv[u]; }
        }
        for (int m = 1; m < 64; m <<= 1) {
            s  += __shfl_xor(s,  m, 64);
            ss += __shfl_xor(ss, m, 64);
        }
        __shared__ float red[8];
        int wid = threadIdx.x >> 6, lane = threadIdx.x & 63;
        if (lane == 0) { red[wid * 2] = s; red[wid * 2 + 1] = ss; }
        __syncthreads();
        if (threadIdx.x == 0) {
            float ts  = red[0] + red[2] + red[4] + red[6];
            float tss = red[1] + red[3] + red[5] + red[7];
            atomicAdd(&stats[grp * 2],     ts);
            atomicAdd(&stats[grp * 2 + 1], tss);
        }
    } else {
        // ---- weight f32 -> bf16 ----
        const int wb = bid - 256;           // 0..511
        const int mat = wb >> 7, chunk = wb & 127;
        const float* src = (mat == 0) ? w0 : (mat == 1) ? w1 : (mat == 2) ? w2 : w3;
        const size_t base = (size_t)chunk * 2048 + (size_t)threadIdx.x * 8;
        f32x4 a = *(const f32x4*)(src + base);
        f32x4 b2 = *(const f32x4*)(src + base + 4);
        u16x8 o;
        for (int u = 0; u < 4; ++u) { o[u] = f2bf(a[u]); o[u + 4] = f2bf(b2[u]); }
        *(u16x8*)(dst + (size_t)mat * 262144 + base) = o;
    }
}

// ---------------------------------------------------------------------------
// 1) GroupNorm apply + transpose: x[b,c,l] (f32) -> hT[b,l,c] (bf16).
//    64x64 tiles through LDS.
// ---------------------------------------------------------------------------
__global__ __launch_bounds__(256) void gn_apply_k(const float* __restrict__ x,
                                                  const float* __restrict__ gns,
                                                  const float* __restrict__ gnb,
                                                  const float* __restrict__ stats,
                                                  u16* __restrict__ hT) {
    __shared__ u16 Ts[64 * 72];
    const int b = blockIdx.z, c0 = blockIdx.y * 64, l0 = blockIdx.x * 64;
    const int g = c0 >> 7;
    const int tid = threadIdx.x;

    float sum   = stats[(b * NGRP + g) * 2];
    float sumsq = stats[(b * NGRP + g) * 2 + 1];
    const float invN = 1.f / (float)GSIZE;
    float mean = sum * invN;
    float var  = sumsq * invN - mean * mean;
    float rstd = rsqrtf(var + 1e-6f);

    for (int i = 0; i < 4; ++i) {
        int cid = tid + i * 256;          // 0..1023
        int row = cid >> 4, c4 = cid & 15;
        int c = c0 + row;
        float sc = gns[c] * rstd;
        float bi = gnb[c] - mean * sc;
        f32x4 dv = *(const f32x4*)(x + ((size_t)(b * CCH + c)) * LEN + l0 + c4 * 4);
        for (int u = 0; u < 4; ++u)
            Ts[row * 72 + c4 * 4 + u] = f2bf(dv[u] * sc + bi);
    }
    __syncthreads();
    for (int i = 0; i < 2; ++i) {
        int cid = tid + i * 256;          // 0..511
        int lrow = cid >> 3, c8 = cid & 7;
        u16x8 ov;
        for (int u = 0; u < 8; ++u) ov[u] = Ts[(c8 * 8 + u) * 72 + lrow];
        *(u16x8*)(hT + ((size_t)b * LEN + l0 + lrow) * CCH + c0 + c8 * 8) = ov;
    }
}

// ---------------------------------------------------------------------------
// 2) Fused QKV GEMM: blocks 0..1023 = mode0 (A=hT m=l, B=wq/wk n=o -> qT/kT),
//    1024..1535 = mode1 (A=wv m=o, B=hT n=l -> v[b,c,l]). Uniform per-block
//    branch; shared 128x128xK=512 dbuf K-loop (BK=64, 4 waves 2x2).
// ---------------------------------------------------------------------------
__global__ __launch_bounds__(256, 2) void gemm01_k(const u16* __restrict__ hT,
                                                   const u16* __restrict__ wq_bf,
                                                   const u16* __restrict__ wk_bf,
                                                   const u16* __restrict__ wv_bf,
                                                   const float* __restrict__ bq,
                                                   const float* __restrict__ bk,
                                                   const float* __restrict__ bv,
                                                   u16* __restrict__ qT,
                                                   u16* __restrict__ kT,
                                                   u16* __restrict__ vbuf) {
    __shared__ u16 As[2][128 * 64];
    __shared__ u16 Bs[2][128 * 64];
    const int bid = blockIdx.x;
    const bool mode0 = (bid < 1024);
    int b, m0, n0;
    const u16 *Arow, *Brow;
    if (mode0) {
        b = bid >> 7; m0 = ((bid >> 3) & 15) * 128; n0 = (bid & 7) * 128;
        Arow = hT + ((size_t)b * LEN + m0) * 512;
        Brow = (n0 < 512) ? (wq_bf + (size_t)n0 * 512)
                          : (wk_bf + (size_t)(n0 - 512) * 512);
    } else {
        int bid2 = bid - 1024;
        b = bid2 >> 6; m0 = ((bid2 >> 4) & 3) * 128; n0 = (bid2 & 15) * 128;
        Arow = wv_bf + (size_t)m0 * 512;
        Brow = hT + ((size_t)b * LEN + n0) * 512;
    }

    const int tid = threadIdx.x;
    const int lane = tid & 63, wid = tid >> 6;
    const int quad = lane >> 4, l15 = lane & 15;
    const int wm = (wid & 1) * 64, wn = (wid >> 1) * 64;

    f32x4 acc[4][4] = {};
    const int srl = lane >> 3, scl = lane & 7;

    // prologue: stage k-tile 0 into buffer 0
#pragma unroll
    for (int i = 0; i < 4; ++i) {
        int rloc = wid * 32 + i * 8 + srl;
        int lc = scl ^ (rloc & 7);
        async16(Arow + (size_t)rloc * 512 + lc * 8, &As[0][(wid * 32 + i * 8) * 64]);
        async16(Brow + (size_t)rloc * 512 + lc * 8, &Bs[0][(wid * 32 + i * 8) * 64]);
    }
    __syncthreads();

    for (int kk = 0; kk < 8; ++kk) {
        const int p = kk & 1;
        if (kk < 7) {
            const int k0n = (kk + 1) * 64;
#pragma unroll
            for (int i = 0; i < 4; ++i) {
                int rloc = wid * 32 + i * 8 + srl;
                int lc = scl ^ (rloc & 7);
                async16(Arow + (size_t)rloc * 512 + k0n + lc * 8,
                        &As[1 - p][(wid * 32 + i * 8) * 64]);
                async16(Brow + (size_t)rloc * 512 + k0n + lc * 8,
                        &Bs[1 - p][(wid * 32 + i * 8) * 64]);
            }
        }
#pragma unroll
        for (int ks = 0; ks < 2; ++ks) {
            bf16x8 af[4], bfr[4];
            for (int t = 0; t < 4; ++t) {
                int ra = wm + t * 16 + l15, rb = wn + t * 16 + l15;
                af[t]  = *(const bf16x8*)(&As[p][ra * 64 + (((ks * 4 + quad) ^ (ra & 7))) * 8]);
                bfr[t] = *(const bf16x8*)(&Bs[p][rb * 64 + (((ks * 4 + quad) ^ (rb & 7))) * 8]);
            }
            for (int mt = 0; mt < 4; ++mt)
                for (int nt = 0; nt < 4; ++nt)
                    acc[mt][nt] = MFMA16(af[mt], bfr[nt], acc[mt][nt]);
        }
        __syncthreads();
    }

    if (mode0) {
        const int col0 = (n0 < 512) ? n0 : n0 - 512;
        const float* biasp = ((n0 < 512) ? bq : bk) + col0;
        u16* outp = (n0 < 512) ? qT : kT;
        for (int nt = 0; nt < 4; ++nt) {
            int nl = wn + nt * 16 + l15;
            float bv_ = biasp[nl];
            for (int mt = 0; mt < 4; ++mt)
                for (int r = 0; r < 4; ++r) {
                    int ml = wm + mt * 16 + quad * 4 + r;
                    size_t idx = ((size_t)b * LEN + m0 + ml) * 512 + col0 + nl;
                    outp[idx] = f2bf(acc[mt][nt][r] + bv_);
                }
        }
    } else {
        for (int mt = 0; mt < 4; ++mt)
            for (int r = 0; r < 4; ++r) {
                int ml = wm + mt * 16 + quad * 4 + r;
                float bv_ = bv[m0 + ml];
                for (int nt = 0; nt < 4; ++nt) {
                    int nl = wn + nt * 16 + l15;
                    size_t idx = ((size_t)(b * 512 + m0 + ml)) * LEN + n0 + nl;
                    vbuf[idx] = f2bf(acc[mt][nt][r] + bv_);
                }
            }
    }
}

// ---------------------------------------------------------------------------
// 3) GEMM MODE 2 (out-proj + residual): A=wo (m=o), B=attnT[b] (n=l) ->
//    out[b,c,l] f32 + bias + x. Same dbuf K-loop.
// ---------------------------------------------------------------------------
__global__ __launch_bounds__(256, 2) void gemm2_k(const u16* __restrict__ A0,
                                                  const u16* __restrict__ B0,
                                                  const float* __restrict__ bias0,
                                                  const float* __restrict__ resid,
                                                  float* __restrict__ out0) {
    __shared__ u16 As[2][128 * 64];
    __shared__ u16 Bs[2][128 * 64];
    const int b  = blockIdx.z;
    const int n0 = blockIdx.x * 128;
    const int m0 = blockIdx.y * 128;
    const int tid = threadIdx.x;
    const int lane = tid & 63, wid = tid >> 6;
    const int quad = lane >> 4, l15 = lane & 15;
    const int wm = (wid & 1) * 64, wn = (wid >> 1) * 64;

    const u16* Arow = A0 + (size_t)m0 * 512;
    const u16* Brow = B0 + ((size_t)b * LEN + n0) * 512;

    f32x4 acc[4][4] = {};
    const int srl = lane >> 3, scl = lane & 7;

#pragma unroll
    for (int i = 0; i < 4; ++i) {
        int rloc = wid * 32 + i * 8 + srl;
        int lc = scl ^ (rloc & 7);
        async16(Arow + (size_t)rloc * 512 + lc * 8, &As[0][(wid * 32 + i * 8) * 64]);
        async16(Brow + (size_t)rloc * 512 + lc * 8, &Bs[0][(wid * 32 + i * 8) * 64]);
    }
    __syncthreads();

    for (int kk = 0; kk < 8; ++kk) {
        const int p = kk & 1;
        if (kk < 7) {
            const int k0n = (kk + 1) * 64;
#pragma unroll
            for (int i = 0; i < 4; ++i) {
                int rloc = wid * 32 + i * 8 + srl;
                int lc = scl ^ (rloc & 7);
                async16(Arow + (size_t)rloc * 512 + k0n + lc * 8,
                        &As[1 - p][(wid * 32 + i * 8) * 64]);
                async16(Brow + (size_t)rloc * 512 + k0n + lc * 8,
                        &Bs[1 - p][(wid * 32 + i * 8) * 64]);
            }
        }
#pragma unroll
        for (int ks = 0; ks < 2; ++ks) {
            bf16x8 af[4], bfr[4];
            for (int t = 0; t < 4; ++t) {
                int ra = wm + t * 16 + l15, rb = wn + t * 16 + l15;
                af[t]  = *(const bf16x8*)(&As[p][ra * 64 + (((ks * 4 + quad) ^ (ra & 7))) * 8]);
                bfr[t] = *(const bf16x8*)(&Bs[p][rb * 64 + (((ks * 4 + quad) ^ (rb & 7))) * 8]);
            }
            for (int mt = 0; mt < 4; ++mt)
                for (int nt = 0; nt < 4; ++nt)
                    acc[mt][nt] = MFMA16(af[mt], bfr[nt], acc[mt][nt]);
        }
        __syncthreads();
    }

    for (int mt = 0; mt < 4; ++mt)
        for (int r = 0; r < 4; ++r) {
            int ml = wm + mt * 16 + quad * 4 + r;
            float bv_ = bias0[m0 + ml];
            for (int nt = 0; nt < 4; ++nt) {
                int nl = wn + nt * 16 + l15;
                size_t idx = ((size_t)(b * 512 + m0 + ml)) * LEN + n0 + nl;
                out0[idx] = acc[mt][nt][r] + bv_ + resid[idx];
            }
        }
}

// ---------------------------------------------------------------------------
// 4) Flash attention (R8 structure + XCD swizzle): S^T form, 64-key j-tiles,
// K/V LDS double-buffered, partial-vmcnt pipeline, 512-thread blocks
// (8 waves), wave owns 16 q-rows of the 128-row Q tile.
// Grid 512 linear: xcd = bid&7; each XCD owns one batch's 4 heads
// (K/V slice = 4MB = its L2; R9 measured FETCH 139->29MB with this map).
// Per iter: issue K(jt+1)/V(jt+1); vm<=6 (K(jt) landed); barrier;
// QK+softmax; vm<=4+lgkm0; barrier; P overlays Ks[p]; PV; lgkm0; barrier.
// ---------------------------------------------------------------------------
__global__ __launch_bounds__(512, 4) void attn_k(const u16* __restrict__ qT,
                                                 const u16* __restrict__ kT,
                                                 const u16* __restrict__ v,
                                                 u16* __restrict__ attnT) {
    __shared__ u16 Ks[2][64 * 128];   // K tile; retired buffer doubles as P[128x64]
    __shared__ u16 Vs[2][128 * 64];
    // XCD-aware decode: xcd owns bh = xcd*4 .. xcd*4+3 (one batch's 4 heads)
    const int bid = blockIdx.x;
    const int xcd = bid & 7, slot = bid >> 3;      // 64 slots per XCD
    const int bh  = xcd * 4 + (slot >> 4);
    const int qt  = slot & 15;
    const int b = bh >> 2, h = bh & 3;
    const int i0 = qt * 128;

    const int tid = threadIdx.x, lane = tid & 63, wid = tid >> 6;  // wid 0..7
    const int quad = lane >> 4, l15 = lane & 15;
    const int mrow = wid * 16 + l15;          // this lane's q-row within tile

    // Q B-frags for this wave's 16 m-rows
    bf16x8 qa[4];
    for (int ks = 0; ks < 4; ++ks)
        qa[ks] = *(const bf16x8*)(qT + ((size_t)b * LEN + i0 + mrow) * 512 + h * HD +
                                  ks * 32 + quad * 8);

    float mst = -3.0e38f, lst = 0.f;          // per-lane (m), quad-replicated
    f32x4 oacc[8] = {};

    const float SL2E = 0.08838834764831845f * 1.4426950408889634f; // scale*log2e

    // staging geometry + loop-carried global pointers (advance one j-tile)
    const u16* kbase = kT + ((size_t)b * LEN) * 512 + h * HD;
    const u16* vbase = v + ((size_t)(b * CCH + h * HD)) * LEN;

    const u16* kgp[2];
    const u16* vgp[2];
    int krow[2], vrow[2];
#pragma unroll
    for (int i = 0; i < 2; ++i) {
        int rk = wid * 8 + i * 4 + (lane >> 4);
        krow[i] = wid * 8 + i * 4;
        kgp[i] = kbase + (size_t)rk * 512 + ((lane & 15) ^ (rk & 7)) * 8;
        int rv = wid * 16 + i * 8 + (lane >> 3);
        vrow[i] = wid * 16 + i * 8;
        vgp[i] = vbase + (size_t)rv * LEN + ((lane & 7) ^ (rv & 7)) * 8;
    }

    // prologue: stage tile 0 into buffer 0, advance pointers to tile 1
#pragma unroll
    for (int i = 0; i < 2; ++i) {
        async16(kgp[i], &Ks[0][krow[i] * 128]);
        async16(vgp[i], &Vs[0][vrow[i] * 64]);
        kgp[i] += 64 * 512;
        vgp[i] += 64;
    }

    for (int jt = 0; jt < 32; ++jt) {
        const int p = jt & 1;

        // issue next tile's DMA into [1-p] (jt=31: harmless re-stage of t31)
#pragma unroll
        for (int i = 0; i < 2; ++i) {
            async16(kgp[i], &Ks[1 - p][krow[i] * 128]);
            async16(vgp[i], &Vs[1 - p][vrow[i] * 64]);
        }
        if (jt < 30) {
#pragma unroll
            for (int i = 0; i < 2; ++i) { kgp[i] += 64 * 512; vgp[i] += 64; }
        }

        __builtin_amdgcn_s_waitcnt(WAIT_VM6);   // K(jt) landed (mine)
        BARRIER();                              // K(jt) landed (all waves)

        // S^T: st[jtn] rows j = jtn*16+quad*4+r, cols m = wid*16+l15
        f32x4 st[4] = {};
#pragma unroll
        for (int jtn = 0; jtn < 4; ++jtn) {
            int r = jtn * 16 + l15;
            for (int ks = 0; ks < 4; ++ks) {
                bf16x8 kf = *(const bf16x8*)(&Ks[p][r * 128 + ((ks * 4 + quad) ^ (r & 7)) * 8]);
                st[jtn] = MFMA16(kf, qa[ks], st[jtn]);
            }
        }

        // online softmax; state per lane (m), quad-replicated
        float rm = -3.0e38f;
        for (int jtn = 0; jtn < 4; ++jtn)
            for (int r = 0; r < 4; ++r) rm = fmaxf(rm, st[jtn][r]);
        rm *= SL2E;
        rm = fmaxf(rm, __shfl_xor(rm, 16, 64));
        rm = fmaxf(rm, __shfl_xor(rm, 32, 64));
        float mnew  = fmaxf(mst, rm);
        float alpha = __builtin_amdgcn_exp2f(mst - mnew);
        mst = mnew;
        float rs = 0.f;
        for (int jtn = 0; jtn < 4; ++jtn)
            for (int r = 0; r < 4; ++r) {
                float pv_ = __builtin_amdgcn_exp2f(st[jtn][r] * SL2E - mnew);
                st[jtn][r] = pv_;
                rs += pv_;
            }
        rs += __shfl_xor(rs, 16, 64);
        rs += __shfl_xor(rs, 32, 64);
        lst = lst * alpha + rs;

        // rescale O only if some lane actually changed max (late iters skip)
        if (__ballot(alpha != 1.0f) != 0ull) {
            float av[4];
            for (int r = 0; r < 4; ++r) av[r] = __shfl(alpha, quad * 4 + r, 16);
            for (int dt = 0; dt < 8; ++dt)
                for (int r = 0; r < 4; ++r) oacc[dt][r] *= av[r];
        }

        __builtin_amdgcn_s_waitcnt(WAIT_VM4_LGKM0);  // V(jt) landed; QK reads retired
        BARRIER();                                   // all waves: V ready, Ks[p] free

        // P[m][j] (bf16, half-up) overlays Ks[p] as [128][64], swizzled
        {
            int m = mrow;
#pragma unroll
            for (int jtn = 0; jtn < 4; ++jtn) {
                u64 packed =  (u64)((fbits(st[jtn][0]) + 0x8000u) >> 16)
                           | ((u64)((fbits(st[jtn][1]) + 0x8000u) >> 16) << 16)
                           | ((u64)((fbits(st[jtn][2]) + 0x8000u) >> 16) << 32)
                           | ((u64)((fbits(st[jtn][3]) + 0x8000u) >> 16) << 48);
                int pc = (jtn * 2 + (quad >> 1)) ^ (m & 7);
                *(u64*)(&Ks[p][m * 64 + pc * 8 + (quad & 1) * 4]) = packed;
            }
        }

        // PV: O[m][d] += P[m][j] * V[d][j]; own wave's P rows -> no barrier
#pragma unroll
        for (int ks = 0; ks < 2; ++ks) {
            bf16x8 pf = *(const bf16x8*)(&Ks[p][mrow * 64 + ((ks * 4 + quad) ^ (mrow & 7)) * 8]);
            for (int dt = 0; dt < 8; ++dt) {
                int d = dt * 16 + l15;
                bf16x8 vf = *(const bf16x8*)(&Vs[p][d * 64 + ((ks * 4 + quad) ^ (d & 7)) * 8]);
                oacc[dt] = MFMA16(pf, vf, oacc[dt]);
            }
        }

        __builtin_amdgcn_s_waitcnt(WAIT_VM4_LGKM0);  // DS retired; prefetch stays out
        BARRIER();                                   // PV done before [p] restage
    }

    float inv = 1.f / lst;
    float iv[4];
    for (int r = 0; r < 4; ++r) iv[r] = __shfl(inv, quad * 4 + r, 16);
    for (int r = 0; r < 4; ++r) {
        int m = i0 + wid * 16 + quad * 4 + r;
        for (int dt = 0; dt < 8; ++dt) {
            int d = dt * 16 + l15;
            attnT[((size_t)b * LEN + m) * 512 + h * HD + d] = f2bf(oacc[dt][r] * iv[r]);
        }
    }
}

// ---------------------------------------------------------------------------
extern "C" void kernel_launch(void* const* d_in, const int* in_sizes, int n_in,
                              void* d_out, int out_size, void* d_ws, size_t ws_size,
                              hipStream_t stream) {
    const float* x   = (const float*)d_in[0];
    const float* gns = (const float*)d_in[1];
    const float* gnb = (const float*)d_in[2];
    const float* wq  = (const float*)d_in[3];
    const float* bq  = (const float*)d_in[4];
    const float* wk  = (const float*)d_in[5];
    const float* bk  = (const float*)d_in[6];
    const float* wv  = (const float*)d_in[7];
    const float* bv  = (const float*)d_in[8];
    const float* wo  = (const float*)d_in[9];
    const float* bo  = (const float*)d_in[10];
    float* out = (float*)d_out;

    const size_t NEL = (size_t)BATCH * CCH * LEN;   // 8388608
    float* stats = (float*)d_ws;                     // 64 floats @ 0
    u16* wcat  = (u16*)((char*)d_ws + 256);          // 4 x 512x512 bf16 weights
    u16* hT    = wcat + 4 * 262144;                  // bf16 [B,L,C]; reused as attnT
    u16* qT    = hT + NEL;
    u16* kT    = qT + NEL;
    u16* vbuf  = kT + NEL;
    u16* attnT = hT;   // hT dead after gemm01; alias to save 16 MB

    const u16* wq_bf = wcat;
    const u16* wk_bf = wcat + 262144;
    const u16* wv_bf = wcat + 2 * 262144;
    const u16* wo_bf = wcat + 3 * 262144;

    hipMemsetAsync(d_ws, 0, 256, stream);
    prep_k<<<768, 256, 0, stream>>>(x, stats, wq, wk, wv, wo, wcat);
    gn_apply_k<<<dim3(32, 8, 8), 256, 0, stream>>>(x, gns, gnb, stats, hT);
    gemm01_k<<<1536, 256, 0, stream>>>(hT, wq_bf, wk_bf, wv_bf, bq, bk, bv, qT, kT, vbuf);
    attn_k<<<512, 512, 0, stream>>>(qT, kT, vbuf, attnT);
    gemm2_k<<<dim3(16, 4, 8), 256, 0, stream>>>(wo_bf, attnT, bo, x, out);
}

// Round 11
// 262.268 us; speedup vs baseline: 1.3319x; 1.0248x over previous
//
#include <hip/hip_runtime.h>

// ---------------------------------------------------------------------------
// AttnBlock: GroupNorm -> QKV (1x1 conv) -> 4-head attention (L=2048, hd=128)
//            -> out proj -> residual.   B=8, C=512, L=2048, G=4, NH=4.
// Storage dtype: float32. Internal compute: bf16 MFMA, f32 accumulation.
// R11: attention rebuilt on 32x32x16 MFMA (same fragment bytes, 2x FLOPs ->
//      LDS reads per FLOP halved; R10 showed attn is LDS-read-bound at ~78%
//      of wall). 256-thr blocks, wave owns 32 q-rows with m = lane&31 ->
//      softmax state and O-rescale fully lane-local (1 shfl per reduction).
//      Keeps R10's XCD swizzle (FETCH 24MB), dbuf DMA, partial-vmcnt
//      (recounted vm<=12 / vm<=8). Other kernels unchanged.
// ---------------------------------------------------------------------------

typedef unsigned short u16;
typedef unsigned int   u32;
typedef unsigned long long u64;
typedef __attribute__((ext_vector_type(8)))  short          bf16x8;  // MFMA A/B frag
typedef __attribute__((ext_vector_type(4)))  float          f32x4;   // 16x16 C/D
typedef __attribute__((ext_vector_type(16))) float          f32x16;  // 32x32 C/D
typedef __attribute__((ext_vector_type(4)))  unsigned int   u32x4;
typedef __attribute__((ext_vector_type(8)))  unsigned short u16x8;

#define MFMA16(a, b, c) __builtin_amdgcn_mfma_f32_16x16x32_bf16((a), (b), (c), 0, 0, 0)
#define MFMA32(a, b, c) __builtin_amdgcn_mfma_f32_32x32x16_bf16((a), (b), (c), 0, 0, 0)

// s_waitcnt simm16: vmcnt[3:0]+[15:14], expcnt[6:4], lgkmcnt[13:8]
#define WAIT_VM12        3964   // vm<=12 (0xF7C)
#define WAIT_VM8_LGKM0    120   // vm<=8, lgkm=0 (0x78)
#define WAIT_VM6         3958   // vm<=6
#define WAIT_VM4_LGKM0    116   // vm<=4, lgkm=0
#define WAIT_LGKM0      49279   // lgkm=0, vm untouched (0xC07F)
#define BARRIER() __builtin_amdgcn_s_barrier()

__device__ __forceinline__ u16 f2bf(float f) {
    union { float f; unsigned int i; } cv;
    cv.f = f;
    unsigned int u = cv.i;
    u += 0x7fffu + ((u >> 16) & 1);   // RNE
    return (u16)(u >> 16);
}
__device__ __forceinline__ u32 fbits(float f) {
    union { float f; unsigned int i; } cv; cv.f = f; return cv.i;
}

// async 16B global->LDS (DMA; lands at lds_base + lane*16)
__device__ __forceinline__ void async16(const u16* g, u16* l) {
    __builtin_amdgcn_global_load_lds(
        (const __attribute__((address_space(1))) unsigned int*)g,
        (__attribute__((address_space(3))) unsigned int*)l, 16, 0, 0);
}

#define BATCH 8
#define CCH   512
#define LEN   2048
#define NGRP  4
#define NHEAD 4
#define HD    128
#define GSIZE (128 * 2048)   // elements per (b, group)

// ---------------------------------------------------------------------------
// 0) Fused prep: blocks 0..255 = GroupNorm partial stats; 256..767 = weight
//    conversion (4 x 512x512 f32 -> bf16). Independent work, one dispatch.
// ---------------------------------------------------------------------------
__global__ __launch_bounds__(256) void prep_k(const float* __restrict__ x,
                                              float* __restrict__ stats,
                                              const float* __restrict__ w0,
                                              const float* __restrict__ w1,
                                              const float* __restrict__ w2,
                                              const float* __restrict__ w3,
                                              u16* __restrict__ dst) {
    const int bid = blockIdx.x;
    if (bid < 256) {
        const int grp   = bid >> 3;         // b*4+g
        const int chunk = bid & 7;
        const int b = grp >> 2, g = grp & 3;
        const float* base = x + ((size_t)(b * CCH + g * 128 + chunk * 16)) * LEN;

        float s = 0.f, ss = 0.f;
        for (int i = 0; i < 32; ++i) {
            int cid = threadIdx.x + i * 256;
            f32x4 dv = *(const f32x4*)(base + (size_t)cid * 4);
            for (int u = 0; u < 4; ++u) { s += dv[u]; ss += dv[u] * dv[u]; }
        }
        for (int m = 1; m < 64; m <<= 1) {
            s  += __shfl_xor(s,  m, 64);
            ss += __shfl_xor(ss, m, 64);
        }
        __shared__ float red[8];
        int wid = threadIdx.x >> 6, lane = threadIdx.x & 63;
        if (lane == 0) { red[wid * 2] = s; red[wid * 2 + 1] = ss; }
        __syncthreads();
        if (threadIdx.x == 0) {
            float ts  = red[0] + red[2] + red[4] + red[6];
            float tss = red[1] + red[3] + red[5] + red[7];
            atomicAdd(&stats[grp * 2],     ts);
            atomicAdd(&stats[grp * 2 + 1], tss);
        }
    } else {
        const int wb = bid - 256;           // 0..511
        const int mat = wb >> 7, chunk = wb & 127;
        const float* src = (mat == 0) ? w0 : (mat == 1) ? w1 : (mat == 2) ? w2 : w3;
        const size_t base = (size_t)chunk * 2048 + (size_t)threadIdx.x * 8;
        f32x4 a = *(const f32x4*)(src + base);
        f32x4 b2 = *(const f32x4*)(src + base + 4);
        u16x8 o;
        for (int u = 0; u < 4; ++u) { o[u] = f2bf(a[u]); o[u + 4] = f2bf(b2[u]); }
        *(u16x8*)(dst + (size_t)mat * 262144 + base) = o;
    }
}

// ---------------------------------------------------------------------------
// 1) GroupNorm apply + transpose: x[b,c,l] (f32) -> hT[b,l,c] (bf16).
// ---------------------------------------------------------------------------
__global__ __launch_bounds__(256) void gn_apply_k(const float* __restrict__ x,
                                                  const float* __restrict__ gns,
                                                  const float* __restrict__ gnb,
                                                  const float* __restrict__ stats,
                                                  u16* __restrict__ hT) {
    __shared__ u16 Ts[64 * 72];
    const int b = blockIdx.z, c0 = blockIdx.y * 64, l0 = blockIdx.x * 64;
    const int g = c0 >> 7;
    const int tid = threadIdx.x;

    float sum   = stats[(b * NGRP + g) * 2];
    float sumsq = stats[(b * NGRP + g) * 2 + 1];
    const float invN = 1.f / (float)GSIZE;
    float mean = sum * invN;
    float var  = sumsq * invN - mean * mean;
    float rstd = rsqrtf(var + 1e-6f);

    for (int i = 0; i < 4; ++i) {
        int cid = tid + i * 256;
        int row = cid >> 4, c4 = cid & 15;
        int c = c0 + row;
        float sc = gns[c] * rstd;
        float bi = gnb[c] - mean * sc;
        f32x4 dv = *(const f32x4*)(x + ((size_t)(b * CCH + c)) * LEN + l0 + c4 * 4);
        for (int u = 0; u < 4; ++u)
            Ts[row * 72 + c4 * 4 + u] = f2bf(dv[u] * sc + bi);
    }
    __syncthreads();
    for (int i = 0; i < 2; ++i) {
        int cid = tid + i * 256;
        int lrow = cid >> 3, c8 = cid & 7;
        u16x8 ov;
        for (int u = 0; u < 8; ++u) ov[u] = Ts[(c8 * 8 + u) * 72 + lrow];
        *(u16x8*)(hT + ((size_t)b * LEN + l0 + lrow) * CCH + c0 + c8 * 8) = ov;
    }
}

// ---------------------------------------------------------------------------
// 2) Fused QKV GEMM (mode0 = qT/kT, mode1 = v), dbuf K-loop. Unchanged R10.
// ---------------------------------------------------------------------------
__global__ __launch_bounds__(256, 2) void gemm01_k(const u16* __restrict__ hT,
                                                   const u16* __restrict__ wq_bf,
                                                   const u16* __restrict__ wk_bf,
                                                   const u16* __restrict__ wv_bf,
                                                   const float* __restrict__ bq,
                                                   const float* __restrict__ bk,
                                                   const float* __restrict__ bv,
                                                   u16* __restrict__ qT,
                                                   u16* __restrict__ kT,
                                                   u16* __restrict__ vbuf) {
    __shared__ u16 As[2][128 * 64];
    __shared__ u16 Bs[2][128 * 64];
    const int bid = blockIdx.x;
    const bool mode0 = (bid < 1024);
    int b, m0, n0;
    const u16 *Arow, *Brow;
    if (mode0) {
        b = bid >> 7; m0 = ((bid >> 3) & 15) * 128; n0 = (bid & 7) * 128;
        Arow = hT + ((size_t)b * LEN + m0) * 512;
        Brow = (n0 < 512) ? (wq_bf + (size_t)n0 * 512)
                          : (wk_bf + (size_t)(n0 - 512) * 512);
    } else {
        int bid2 = bid - 1024;
        b = bid2 >> 6; m0 = ((bid2 >> 4) & 3) * 128; n0 = (bid2 & 15) * 128;
        Arow = wv_bf + (size_t)m0 * 512;
        Brow = hT + ((size_t)b * LEN + n0) * 512;
    }

    const int tid = threadIdx.x;
    const int lane = tid & 63, wid = tid >> 6;
    const int quad = lane >> 4, l15 = lane & 15;
    const int wm = (wid & 1) * 64, wn = (wid >> 1) * 64;

    f32x4 acc[4][4] = {};
    const int srl = lane >> 3, scl = lane & 7;

#pragma unroll
    for (int i = 0; i < 4; ++i) {
        int rloc = wid * 32 + i * 8 + srl;
        int lc = scl ^ (rloc & 7);
        async16(Arow + (size_t)rloc * 512 + lc * 8, &As[0][(wid * 32 + i * 8) * 64]);
        async16(Brow + (size_t)rloc * 512 + lc * 8, &Bs[0][(wid * 32 + i * 8) * 64]);
    }
    __syncthreads();

    for (int kk = 0; kk < 8; ++kk) {
        const int p = kk & 1;
        if (kk < 7) {
            const int k0n = (kk + 1) * 64;
#pragma unroll
            for (int i = 0; i < 4; ++i) {
                int rloc = wid * 32 + i * 8 + srl;
                int lc = scl ^ (rloc & 7);
                async16(Arow + (size_t)rloc * 512 + k0n + lc * 8,
                        &As[1 - p][(wid * 32 + i * 8) * 64]);
                async16(Brow + (size_t)rloc * 512 + k0n + lc * 8,
                        &Bs[1 - p][(wid * 32 + i * 8) * 64]);
            }
        }
#pragma unroll
        for (int ks = 0; ks < 2; ++ks) {
            bf16x8 af[4], bfr[4];
            for (int t = 0; t < 4; ++t) {
                int ra = wm + t * 16 + l15, rb = wn + t * 16 + l15;
                af[t]  = *(const bf16x8*)(&As[p][ra * 64 + (((ks * 4 + quad) ^ (ra & 7))) * 8]);
                bfr[t] = *(const bf16x8*)(&Bs[p][rb * 64 + (((ks * 4 + quad) ^ (rb & 7))) * 8]);
            }
            for (int mt = 0; mt < 4; ++mt)
                for (int nt = 0; nt < 4; ++nt)
                    acc[mt][nt] = MFMA16(af[mt], bfr[nt], acc[mt][nt]);
        }
        __syncthreads();
    }

    if (mode0) {
        const int col0 = (n0 < 512) ? n0 : n0 - 512;
        const float* biasp = ((n0 < 512) ? bq : bk) + col0;
        u16* outp = (n0 < 512) ? qT : kT;
        for (int nt = 0; nt < 4; ++nt) {
            int nl = wn + nt * 16 + l15;
            float bv_ = biasp[nl];
            for (int mt = 0; mt < 4; ++mt)
                for (int r = 0; r < 4; ++r) {
                    int ml = wm + mt * 16 + quad * 4 + r;
                    size_t idx = ((size_t)b * LEN + m0 + ml) * 512 + col0 + nl;
                    outp[idx] = f2bf(acc[mt][nt][r] + bv_);
                }
        }
    } else {
        for (int mt = 0; mt < 4; ++mt)
            for (int r = 0; r < 4; ++r) {
                int ml = wm + mt * 16 + quad * 4 + r;
                float bv_ = bv[m0 + ml];
                for (int nt = 0; nt < 4; ++nt) {
                    int nl = wn + nt * 16 + l15;
                    size_t idx = ((size_t)(b * 512 + m0 + ml)) * LEN + n0 + nl;
                    vbuf[idx] = f2bf(acc[mt][nt][r] + bv_);
                }
            }
    }
}

// ---------------------------------------------------------------------------
// 3) GEMM MODE 2 (out-proj + residual). Unchanged R10.
// ---------------------------------------------------------------------------
__global__ __launch_bounds__(256, 2) void gemm2_k(const u16* __restrict__ A0,
                                                  const u16* __restrict__ B0,
                                                  const float* __restrict__ bias0,
                                                  const float* __restrict__ resid,
                                                  float* __restrict__ out0) {
    __shared__ u16 As[2][128 * 64];
    __shared__ u16 Bs[2][128 * 64];
    const int b  = blockIdx.z;
    const int n0 = blockIdx.x * 128;
    const int m0 = blockIdx.y * 128;
    const int tid = threadIdx.x;
    const int lane = tid & 63, wid = tid >> 6;
    const int quad = lane >> 4, l15 = lane & 15;
    const int wm = (wid & 1) * 64, wn = (wid >> 1) * 64;

    const u16* Arow = A0 + (size_t)m0 * 512;
    const u16* Brow = B0 + ((size_t)b * LEN + n0) * 512;

    f32x4 acc[4][4] = {};
    const int srl = lane >> 3, scl = lane & 7;

#pragma unroll
    for (int i = 0; i < 4; ++i) {
        int rloc = wid * 32 + i * 8 + srl;
        int lc = scl ^ (rloc & 7);
        async16(Arow + (size_t)rloc * 512 + lc * 8, &As[0][(wid * 32 + i * 8) * 64]);
        async16(Brow + (size_t)rloc * 512 + lc * 8, &Bs[0][(wid * 32 + i * 8) * 64]);
    }
    __syncthreads();

    for (int kk = 0; kk < 8; ++kk) {
        const int p = kk & 1;
        if (kk < 7) {
            const int k0n = (kk + 1) * 64;
#pragma unroll
            for (int i = 0; i < 4; ++i) {
                int rloc = wid * 32 + i * 8 + srl;
                int lc = scl ^ (rloc & 7);
                async16(Arow + (size_t)rloc * 512 + k0n + lc * 8,
                        &As[1 - p][(wid * 32 + i * 8) * 64]);
                async16(Brow + (size_t)rloc * 512 + k0n + lc * 8,
                        &Bs[1 - p][(wid * 32 + i * 8) * 64]);
            }
        }
#pragma unroll
        for (int ks = 0; ks < 2; ++ks) {
            bf16x8 af[4], bfr[4];
            for (int t = 0; t < 4; ++t) {
                int ra = wm + t * 16 + l15, rb = wn + t * 16 + l15;
                af[t]  = *(const bf16x8*)(&As[p][ra * 64 + (((ks * 4 + quad) ^ (ra & 7))) * 8]);
                bfr[t] = *(const bf16x8*)(&Bs[p][rb * 64 + (((ks * 4 + quad) ^ (rb & 7))) * 8]);
            }
            for (int mt = 0; mt < 4; ++mt)
                for (int nt = 0; nt < 4; ++nt)
                    acc[mt][nt] = MFMA16(af[mt], bfr[nt], acc[mt][nt]);
        }
        __syncthreads();
    }

    for (int mt = 0; mt < 4; ++mt)
        for (int r = 0; r < 4; ++r) {
            int ml = wm + mt * 16 + quad * 4 + r;
            float bv_ = bias0[m0 + ml];
            for (int nt = 0; nt < 4; ++nt) {
                int nl = wn + nt * 16 + l15;
                size_t idx = ((size_t)(b * 512 + m0 + ml)) * LEN + n0 + nl;
                out0[idx] = acc[mt][nt][r] + bv_ + resid[idx];
            }
        }
}

// ---------------------------------------------------------------------------
// 4) Flash attention v10: 32x32x16 MFMA. 256 threads, 4 waves, wave owns
// 32 q-rows (m = lane&31 per lane -> softmax & rescale lane-local).
// Q-tile 128, j-tile 64, 32 iters. LDS: Ks[2][64x128] + Vs[2][128x64] = 64KB;
// P[128x64] overlays Ks[p]. 16B-unit XOR swizzle everywhere.
// Per iter: issue K(jt+1)x4 + V(jt+1)x4 DMA; vm<=12 (K(jt) landed); barrier;
// QK (2 S^T tiles x 8 MFMA, A=K LDS, B=Q regs); lane-local softmax (1 shfl);
// vm<=8+lgkm0 (V(jt) landed); barrier; P->Ks[p]; PV (A=V, B=P; 16+4 reads,
// 16 MFMA); lgkm0; barrier. XCD swizzle: xcd=bid&7 owns one batch's 4 heads.
// ---------------------------------------------------------------------------
__global__ __launch_bounds__(256, 2) void attn_k(const u16* __restrict__ qT,
                                                 const u16* __restrict__ kT,
                                                 const u16* __restrict__ v,
                                                 u16* __restrict__ attnT) {
    __shared__ u16 Ks[2][64 * 128];   // K tile; Ks[p] doubles as P[128][64]
    __shared__ u16 Vs[2][128 * 64];
    const int bid = blockIdx.x;
    const int xcd = bid & 7, slot = bid >> 3;      // 64 slots per XCD
    const int bh  = xcd * 4 + (slot >> 4);
    const int qt  = slot & 15;
    const int b = bh >> 2, h = bh & 3;
    const int i0 = qt * 128;

    const int tid = threadIdx.x, lane = tid & 63, wg = tid >> 6;   // wg 0..3
    const int l31 = lane & 31, half = lane >> 5;
    const int mrow = wg * 32 + l31;    // this lane's q-row within the 128-tile

    // Q B-frags: B[k=d][n=m], lane n=l31, k = ks*16 + half*8 + e
    bf16x8 qa[8];
#pragma unroll
    for (int ks = 0; ks < 8; ++ks)
        qa[ks] = *(const bf16x8*)(qT + ((size_t)b * LEN + i0 + mrow) * 512 + h * HD +
                                  ks * 16 + half * 8);

    float mst = -3.0e38f, lst = 0.f;   // per-lane (m = l31), half-replicated
    f32x16 oacc[4] = {};               // O^T[d][m]: 4 d-tiles of 32

    const float SL2E = 0.08838834764831845f * 1.4426950408889634f; // scale*log2e

    // DMA staging: K 4 instr (4 rows x 16 units each), V 4 instr (8 rows x 8)
    const u16* kbase = kT + ((size_t)b * LEN) * 512 + h * HD;
    const u16* vbase = v + ((size_t)(b * CCH + h * HD)) * LEN;
    const u16* kgp[4];
    const u16* vgp[4];
    int krow[4], vrow[4];
#pragma unroll
    for (int i = 0; i < 4; ++i) {
        int rk = wg * 16 + i * 4 + (lane >> 4);
        krow[i] = wg * 16 + i * 4;
        kgp[i] = kbase + (size_t)rk * 512 + ((lane & 15) ^ (rk & 7)) * 8;
        int rv = wg * 32 + i * 8 + (lane >> 3);
        vrow[i] = wg * 32 + i * 8;
        vgp[i] = vbase + (size_t)rv * LEN + ((lane & 7) ^ (rv & 7)) * 8;
    }

    // prologue: stage tile 0 into buffer 0, advance to tile 1
#pragma unroll
    for (int i = 0; i < 4; ++i) {
        async16(kgp[i], &Ks[0][krow[i] * 128]);
        async16(vgp[i], &Vs[0][vrow[i] * 64]);
        kgp[i] += 64 * 512;
        vgp[i] += 64;
    }

    for (int jt = 0; jt < 32; ++jt) {
        const int p = jt & 1;

        // issue next tile's DMA into [1-p] (jt=31: harmless re-stage)
#pragma unroll
        for (int i = 0; i < 4; ++i) async16(kgp[i], &Ks[1 - p][krow[i] * 128]);
#pragma unroll
        for (int i = 0; i < 4; ++i) async16(vgp[i], &Vs[1 - p][vrow[i] * 64]);
        if (jt < 30) {
#pragma unroll
            for (int i = 0; i < 4; ++i) { kgp[i] += 64 * 512; vgp[i] += 64; }
        }

        __builtin_amdgcn_s_waitcnt(WAIT_VM12);   // K(jt) landed (mine)
        BARRIER();                               // K(jt) landed (all waves)

        // QK: S^T tiles t=0,1 (j rows t*32.., m cols). A=K frag, B=Q regs.
        f32x16 st[2] = {};
#pragma unroll
        for (int t = 0; t < 2; ++t) {
            int r = t * 32 + l31;
            for (int ks = 0; ks < 8; ++ks) {
                bf16x8 kf = *(const bf16x8*)(&Ks[p][r * 128 + ((ks * 2 + half) ^ (r & 7)) * 8]);
                st[t] = MFMA32(kf, qa[ks], st[t]);
            }
        }

        // lane-local online softmax (m = l31; halves hold disjoint j sets)
        float rm = -3.0e38f;
        for (int t = 0; t < 2; ++t)
            for (int r = 0; r < 16; ++r) rm = fmaxf(rm, st[t][r]);
        rm *= SL2E;
        rm = fmaxf(rm, __shfl_xor(rm, 32, 64));
        float mnew  = fmaxf(mst, rm);
        float alpha = __builtin_amdgcn_exp2f(mst - mnew);
        mst = mnew;
        float rs = 0.f;
        for (int t = 0; t < 2; ++t)
            for (int r = 0; r < 16; ++r) {
                float pv_ = __builtin_amdgcn_exp2f(st[t][r] * SL2E - mnew);
                st[t][r] = pv_;
                rs += pv_;
            }
        rs += __shfl_xor(rs, 32, 64);
        lst = lst * alpha + rs;
        if (__ballot(alpha != 1.0f) != 0ull) {
            for (int dt = 0; dt < 4; ++dt)
                for (int r = 0; r < 16; ++r) oacc[dt][r] *= alpha;
        }

        __builtin_amdgcn_s_waitcnt(WAIT_VM8_LGKM0);  // V(jt) landed; QK reads done
        BARRIER();                                   // all waves: Ks[p] free for P

        // P[m][j] bf16 (half-up) -> Ks[p] as [128][64], 16B-unit swizzle.
        // S^T D-layout: lane m=l31; regs t,g give j = t*32 + g*8 + half*4 + (r&3)
        {
            u16* Pb = &Ks[p][0];
#pragma unroll
            for (int t = 0; t < 2; ++t)
                for (int g = 0; g < 4; ++g) {
                    u64 packed =  (u64)((fbits(st[t][g * 4 + 0]) + 0x8000u) >> 16)
                               | ((u64)((fbits(st[t][g * 4 + 1]) + 0x8000u) >> 16) << 16)
                               | ((u64)((fbits(st[t][g * 4 + 2]) + 0x8000u) >> 16) << 32)
                               | ((u64)((fbits(st[t][g * 4 + 3]) + 0x8000u) >> 16) << 48);
                    int pu = (t * 4 + g) ^ (mrow & 7);
                    *(u64*)(&Pb[mrow * 64 + pu * 8 + half * 4]) = packed;
                }
        }

        // PV: O^T[d][m] += V[d][j] * P[m][j]. A=V frag, B=P frag.
        {
            const u16* Pb = &Ks[p][0];
#pragma unroll
            for (int jb = 0; jb < 4; ++jb) {
                bf16x8 pf = *(const bf16x8*)(&Pb[mrow * 64 + ((jb * 2 + half) ^ (mrow & 7)) * 8]);
                for (int dt = 0; dt < 4; ++dt) {
                    int d = dt * 32 + l31;
                    bf16x8 vf = *(const bf16x8*)(&Vs[p][d * 64 + ((jb * 2 + half) ^ (d & 7)) * 8]);
                    oacc[dt] = MFMA32(vf, pf, oacc[dt]);
                }
            }
        }

        __builtin_amdgcn_s_waitcnt(WAIT_LGKM0);  // my LDS reads retired
        BARRIER();                               // all waves done with [p]
    }

    // epilogue: O[m][d] = oacc/lst. d = dt*32 + g*8 + half*4 + (r&3)
    float inv = 1.f / lst;
    for (int dt = 0; dt < 4; ++dt)
        for (int g = 0; g < 4; ++g) {
            u64 w =  (u64)f2bf(oacc[dt][g * 4 + 0] * inv)
                  | ((u64)f2bf(oacc[dt][g * 4 + 1] * inv) << 16)
                  | ((u64)f2bf(oacc[dt][g * 4 + 2] * inv) << 32)
                  | ((u64)f2bf(oacc[dt][g * 4 + 3] * inv) << 48);
            int c = h * HD + dt * 32 + g * 8 + half * 4;
            *(u64*)(attnT + ((size_t)b * LEN + i0 + mrow) * 512 + c) = w;
        }
}

// ---------------------------------------------------------------------------
extern "C" void kernel_launch(void* const* d_in, const int* in_sizes, int n_in,
                              void* d_out, int out_size, void* d_ws, size_t ws_size,
                              hipStream_t stream) {
    const float* x   = (const float*)d_in[0];
    const float* gns = (const float*)d_in[1];
    const float* gnb = (const float*)d_in[2];
    const float* wq  = (const float*)d_in[3];
    const float* bq  = (const float*)d_in[4];
    const float* wk  = (const float*)d_in[5];
    const float* bk  = (const float*)d_in[6];
    const float* wv  = (const float*)d_in[7];
    const float* bv  = (const float*)d_in[8];
    const float* wo  = (const float*)d_in[9];
    const float* bo  = (const float*)d_in[10];
    float* out = (float*)d_out;

    const size_t NEL = (size_t)BATCH * CCH * LEN;   // 8388608
    float* stats = (float*)d_ws;                     // 64 floats @ 0
    u16* wcat  = (u16*)((char*)d_ws + 256);          // 4 x 512x512 bf16 weights
    u16* hT    = wcat + 4 * 262144;                  // bf16 [B,L,C]; reused as attnT
    u16* qT    = hT + NEL;
    u16* kT    = qT + NEL;
    u16* vbuf  = kT + NEL;
    u16* attnT = hT;   // hT dead after gemm01; alias

    const u16* wq_bf = wcat;
    const u16* wk_bf = wcat + 262144;
    const u16* wv_bf = wcat + 2 * 262144;
    const u16* wo_bf = wcat + 3 * 262144;

    hipMemsetAsync(d_ws, 0, 256, stream);
    prep_k<<<768, 256, 0, stream>>>(x, stats, wq, wk, wv, wo, wcat);
    gn_apply_k<<<dim3(32, 8, 8), 256, 0, stream>>>(x, gns, gnb, stats, hT);
    gemm01_k<<<1536, 256, 0, stream>>>(hT, wq_bf, wk_bf, wv_bf, bq, bk, bv, qT, kT, vbuf);
    attn_k<<<512, 256, 0, stream>>>(qT, kT, vbuf, attnT);
    gemm2_k<<<dim3(16, 4, 8), 256, 0, stream>>>(wo_bf, attnT, bo, x, out);
}